// Round 4
// baseline (1480.529 us; speedup 1.0000x reference)
//
#include <hip/hip_runtime.h>
#include <math.h>

#define NUSER 20000
#define NITEM 20000
#define NNODE 40000
#define MP_USER 20096   // 314*64
#define MP_NODE 40064   // 626*64 = 313*128

typedef unsigned short u16;
typedef __attribute__((ext_vector_type(8))) short bf16x8;   // 8 bf16 = 4 VGPRs
typedef __attribute__((ext_vector_type(4))) float f32x4;

__device__ __forceinline__ float leaky(float v){ return v > 0.0f ? v : 0.01f*v; }
__device__ __forceinline__ u16 f2bf(float f){
  unsigned u = __float_as_uint(f);
  return (u16)((u + 0x7FFFu + ((u>>16)&1u)) >> 16);   // RNE bf16
}
__device__ __forceinline__ float bf2f(u16 h){ return __uint_as_float(((unsigned)h)<<16); }
__device__ __forceinline__ unsigned pack2(u16 a, u16 b){ return (unsigned)a | ((unsigned)b<<16); }

enum { EPI_STORE=0, EPI_TANH=1, EPI_LEAKY_ADD=2, EPI_ACCUM=3 };

// ================= wide-N MFMA GEMM: C[M,N] = epi(A[M,K] @ W[K,N]) =================
// One block covers ALL N columns (BN=Np) -> A fetched exactly once from HBM.
// bf16x3 split (ah*bh + ah*bl + al*bh). Wave tile 32x64 = 2x4 mfma_16x16x32 tiles.
// LDS is k-group-major [kg][row][8]: frag ds_read_b128 = 16 lanes x consecutive 16B,
// conflict-free (R3 row-major layout caused 8-way aliasing, 7.7M SQ_LDS_BANK_CONFLICT).
// ASPLIT: A pre-split bf16 [rows][Kp] padded. else: fp32 A, cvt in staging, guards.
template<int BM, int BN, int EPI, bool ASPLIT>
__global__ __launch_bounds__((BM/32)*(BN/64)*64)
void wgemm_k(const float* __restrict__ A, const u16* __restrict__ Ah, const u16* __restrict__ Al,
             const u16* __restrict__ Bh, const u16* __restrict__ Bl,
             const float* __restrict__ bias, const float* __restrict__ add,
             float* __restrict__ C, int M, int N, int K, int Kp)
{
  constexpr int WC = BN/64, WR = BM/32, T = WR*WC*64;
  __shared__ u16 Ash[4*BM*8], Asl[4*BM*8], Bsh[4*BN*8], Bsl[4*BN*8];
  const int tid = threadIdx.x, lane = tid & 63, wid = tid >> 6;
  const int wrow = wid / WC, wcol = wid % WC;
  const int row0 = blockIdx.y*BM;
  const int fr = lane & 15, kg = lane >> 4;

  f32x4 acc[2][4] = {};

  for (int kt = 0; kt < Kp; kt += 32) {
    if (ASPLIT) {
      constexpr int AG = BM*4;                 // 8-u16 granules per matrix
      #pragma unroll
      for (int i = 0; i < 2*AG/T; i++) {
        int g = tid + i*T;
        int gi = (g < AG) ? g : g - AG;
        int r = gi >> 2, kk = gi & 3;
        size_t ofs = (size_t)(row0+r)*Kp + kt + kk*8;
        int idx = (kk*BM + r)*8;
        if (g < AG) *(uint4*)&Ash[idx] = *(const uint4*)(Ah + ofs);
        else        *(uint4*)&Asl[idx] = *(const uint4*)(Al + ofs);
      }
    } else {
      constexpr int AGF = BM*8;                // 4-float granules
      #pragma unroll
      for (int i = 0; i < AGF/T; i++) {
        int g = tid + i*T;
        int r = g >> 3, kq = g & 7;
        int gr = row0 + r, gk = kt + kq*4;
        float4 f = make_float4(0.f,0.f,0.f,0.f);
        if (gr < M) {
          if (gk + 4 <= K) f = *(const float4*)(A + (size_t)gr*K + gk);
          else {
            float* pf = &f.x;
            #pragma unroll
            for (int j=0;j<4;j++) pf[j] = (gk+j < K) ? A[(size_t)gr*K + gk + j] : 0.f;
          }
        }
        const float* pf = &f.x;
        u16 h[4], l[4];
        #pragma unroll
        for (int j=0;j<4;j++){ h[j]=f2bf(pf[j]); l[j]=f2bf(pf[j]-bf2f(h[j])); }
        int kk = kq >> 1, half = (kq & 1)*4;
        int idx = (kk*BM + r)*8 + half;
        *(uint2*)&Ash[idx] = make_uint2(pack2(h[0],h[1]),pack2(h[2],h[3]));
        *(uint2*)&Asl[idx] = make_uint2(pack2(l[0],l[1]),pack2(l[2],l[3]));
      }
    }
    {
      constexpr int BG = BN*4;
      #pragma unroll
      for (int i = 0; i < 2*BG/T; i++) {
        int g = tid + i*T;
        int gi = (g < BG) ? g : g - BG;
        int r = gi >> 2, kk = gi & 3;
        size_t ofs = (size_t)r*Kp + kt + kk*8;
        int idx = (kk*BN + r)*8;
        if (g < BG) *(uint4*)&Bsh[idx] = *(const uint4*)(Bh + ofs);
        else        *(uint4*)&Bsl[idx] = *(const uint4*)(Bl + ofs);
      }
    }
    __syncthreads();
    bf16x8 ah_[2], al_[2], bh_[4], bl_[4];
    #pragma unroll
    for (int mi=0;mi<2;mi++){
      int idx = (kg*BM + wrow*32 + mi*16 + fr)*8;
      ah_[mi] = *(const bf16x8*)&Ash[idx];
      al_[mi] = *(const bf16x8*)&Asl[idx];
    }
    #pragma unroll
    for (int ni=0;ni<4;ni++){
      int idx = (kg*BN + wcol*64 + ni*16 + fr)*8;
      bh_[ni] = *(const bf16x8*)&Bsh[idx];
      bl_[ni] = *(const bf16x8*)&Bsl[idx];
    }
    #pragma unroll
    for (int mi=0;mi<2;mi++)
      #pragma unroll
      for (int ni=0;ni<4;ni++){
        acc[mi][ni] = __builtin_amdgcn_mfma_f32_16x16x32_bf16(ah_[mi], bh_[ni], acc[mi][ni], 0,0,0);
        acc[mi][ni] = __builtin_amdgcn_mfma_f32_16x16x32_bf16(ah_[mi], bl_[ni], acc[mi][ni], 0,0,0);
        acc[mi][ni] = __builtin_amdgcn_mfma_f32_16x16x32_bf16(al_[mi], bh_[ni], acc[mi][ni], 0,0,0);
      }
    __syncthreads();
  }
  // epilogue: D reg r -> row=(lane>>4)*4+r, col=lane&15 (m89-verified)
  #pragma unroll
  for (int mi=0;mi<2;mi++){
    #pragma unroll
    for (int ni=0;ni<4;ni++){
      int col = wcol*64 + ni*16 + fr;
      if (col >= N) continue;
      #pragma unroll
      for (int r=0;r<4;r++){
        int row = row0 + wrow*32 + mi*16 + kg*4 + r;
        if (row >= M) continue;
        size_t idx = (size_t)row*N + col;
        float v = acc[mi][ni][r];
        if (EPI==EPI_STORE)          C[idx] = v;
        else if (EPI==EPI_TANH)      C[idx] = tanhf(v + bias[col]);
        else if (EPI==EPI_LEAKY_ADD) C[idx] = leaky(v + bias[col]) + add[idx];
        else                         C[idx] += leaky(v + bias[col] + add[idx]);
      }
    }
  }
}

// ============ weight pre-split: W[K][N] fp32 -> Wt_hi/Wt_lo[Np][Kp] bf16 (transposed+padded) ============
struct WDesc { const float* w; u16 *th, *tl; int K, N, Kp, Np; };
struct WPack { WDesc d[12]; };
__global__ void split_w_k(WPack P)
{
  WDesc D = P.d[blockIdx.y];
  int gid = blockIdx.x*256 + threadIdx.x;
  int tot = D.Np * D.Kp;
  if (gid >= tot) return;
  int k = gid / D.Np, n = gid % D.Np;
  float v = (k < D.K && n < D.N) ? D.w[(size_t)k*D.N + n] : 0.f;
  u16 h = f2bf(v);
  D.th[(size_t)n*D.Kp + k] = h;
  D.tl[(size_t)n*D.Kp + k] = f2bf(v - bf2f(h));
}

// ---------------- graph structure ----------------
__global__ void count_deg(const int* __restrict__ ei, int* __restrict__ deg, int E)
{
  int e = blockIdx.x*blockDim.x + threadIdx.x;
  if (e >= 2*E) return;
  int dst = (e < E) ? ei[e+E] : ei[e-E];
  atomicAdd(&deg[dst], 1);
}

__global__ void scan_rowptr(const int* __restrict__ deg, int* __restrict__ row_ptr, int n)
{
  __shared__ int sm[256];
  __shared__ int carry;
  int tid = threadIdx.x;
  if (tid==0) carry = 0;
  __syncthreads();
  for (int base=0; base<n; base+=256) {
    int idx = base + tid;
    int v = (idx < n) ? deg[idx] : 0;
    sm[tid] = v; __syncthreads();
    #pragma unroll
    for (int off=1; off<256; off<<=1) {
      int t = (tid >= off) ? sm[tid-off] : 0;
      __syncthreads();
      sm[tid] += t;
      __syncthreads();
    }
    if (idx < n) row_ptr[idx+1] = carry + sm[tid];
    __syncthreads();
    if (tid==255) carry += sm[255];
    __syncthreads();
  }
  if (tid==0) row_ptr[0] = 0;
}

__global__ void fill_csr(const int* __restrict__ ei, const int* __restrict__ row_ptr,
                         int* __restrict__ row_fill, int* __restrict__ col_src, int E)
{
  int e = blockIdx.x*blockDim.x + threadIdx.x;
  if (e >= 2*E) return;
  int src = ei[e];
  int dst = (e < E) ? ei[e+E] : ei[e-E];
  int pos = row_ptr[dst] + atomicAdd(&row_fill[dst], 1);
  col_src[pos] = src;
}

// guarded vector row load
template<int VW>
__device__ __forceinline__ void loadrow(const float* __restrict__ r, int c0, int L, float* v){
  if (c0 + VW <= L) {
    if (VW==4) *(float4*)v = *(const float4*)r;
    else       *(float2*)v = *(const float2*)r;
  } else {
    #pragma unroll
    for (int j=0;j<VW;j++) v[j] = (c0+j < L) ? r[j] : 0.f;
  }
}

// ---------------- l2norm + bf16 hi/lo split ----------------
template<int VW>   // VW = Kp/64
__global__ __launch_bounds__(256)
void l2norm_split_k(const float* __restrict__ x, u16* __restrict__ xh, u16* __restrict__ xl, int L, int Kp)
{
  int row = (blockIdx.x*blockDim.x + threadIdx.x) >> 6;
  int lane = threadIdx.x & 63;
  if (row >= MP_NODE) return;
  int c0 = lane*VW;
  size_t ofs = (size_t)row*Kp + c0;
  if (row >= NNODE) {
    if (VW==4) { *(uint2*)&xh[ofs] = make_uint2(0,0); *(uint2*)&xl[ofs] = make_uint2(0,0); }
    else       { *(unsigned*)&xh[ofs] = 0; *(unsigned*)&xl[ofs] = 0; }
    return;
  }
  float v[VW];
  loadrow<VW>(x + (size_t)row*L + c0, c0, L, v);
  float ss = 0.f;
  #pragma unroll
  for (int j=0;j<VW;j++) ss += v[j]*v[j];
  #pragma unroll
  for (int o=32;o;o>>=1) ss += __shfl_xor(ss, o);
  float inv = 1.0f / fmaxf(sqrtf(ss), 1e-12f);
  u16 hs[VW], ls[VW];
  #pragma unroll
  for (int j=0;j<VW;j++){
    float val = (c0+j < L) ? v[j]*inv : 0.f;
    hs[j] = f2bf(val); ls[j] = f2bf(val - bf2f(hs[j]));
  }
  if (VW==4) { *(uint2*)&xh[ofs] = make_uint2(pack2(hs[0],hs[1]),pack2(hs[2],hs[3]));
               *(uint2*)&xl[ofs] = make_uint2(pack2(ls[0],ls[1]),pack2(ls[2],ls[3])); }
  else       { *(unsigned*)&xh[ofs] = pack2(hs[0],hs[1]); *(unsigned*)&xl[ofs] = pack2(ls[0],ls[1]); }
}

// ---------------- fused GAT edge logits + per-dst softmax ----------------
template<int VW>
__global__ __launch_bounds__(256)
void gat_alpha_k(const float* __restrict__ xw, const int* __restrict__ row_ptr,
                 const int* __restrict__ col_src, const int* __restrict__ deg,
                 float* __restrict__ alpha, int L)
{
  int node = (blockIdx.x*blockDim.x + threadIdx.x) >> 6;
  int lane = threadIdx.x & 63;
  if (node >= NNODE) return;
  int s = row_ptr[node], e = row_ptr[node+1];
  int cnt = e - s;
  if (cnt == 0) return;
  int c0 = lane*VW;
  float dv[VW];
  loadrow<VW>(xw + (size_t)node*L + c0, c0, L, dv);
  float mylog = -INFINITY;
  for (int p=s; p<e; p++) {
    int src = col_src[p];
    float sv[VW];
    loadrow<VW>(xw + (size_t)src*L + c0, c0, L, sv);
    float dot = 0.f;
    #pragma unroll
    for (int j=0;j<VW;j++) dot = fmaf(dv[j], sv[j], dot);
    #pragma unroll
    for (int o=32;o;o>>=1) dot += __shfl_xor(dot, o);
    float t = dot / sqrtf((float)deg[src]);
    float gate = 1.0f/(1.0f + expf(-t));
    float lg = dot * gate;
    if (cnt <= 64) { if (lane == (p - s)) mylog = lg; }
    else           { if (lane == 0) alpha[p] = lg; }
  }
  if (cnt <= 64) {
    float m = mylog;
    #pragma unroll
    for (int o=32;o;o>>=1) m = fmaxf(m, __shfl_xor(m, o));
    float el = (lane < cnt) ? expf(mylog - m) : 0.f;
    float d = el;
    #pragma unroll
    for (int o=32;o;o>>=1) d += __shfl_xor(d, o);
    float inv = 1.0f / fmaxf(d, 1e-16f);
    if (lane < cnt) alpha[s + lane] = el * inv;
  } else {
    float m = -INFINITY;
    for (int p=s+lane;p<e;p+=64) m = fmaxf(m, alpha[p]);
    #pragma unroll
    for (int o=32;o;o>>=1) m = fmaxf(m, __shfl_xor(m, o));
    float d = 0.f;
    for (int p=s+lane;p<e;p+=64) d += expf(alpha[p]-m);
    #pragma unroll
    for (int o=32;o;o>>=1) d += __shfl_xor(d, o);
    float inv = 1.0f / fmaxf(d, 1e-16f);
    for (int p=s+lane;p<e;p+=64) alpha[p] = expf(alpha[p]-m)*inv;
  }
}

// ---------------- aggregate -> h (bf16 split) ----------------
template<int VW>
__global__ __launch_bounds__(256)
void aggregate_k(const float* __restrict__ xw, const float* __restrict__ alpha,
                 const int* __restrict__ row_ptr, const int* __restrict__ col_src,
                 const float* __restrict__ bias, u16* __restrict__ hh, u16* __restrict__ hl,
                 int L, int Kp)
{
  int node = (blockIdx.x*blockDim.x + threadIdx.x) >> 6;
  int lane = threadIdx.x & 63;
  if (node >= MP_NODE) return;
  int c0 = lane*VW;
  size_t ofs = (size_t)node*Kp + c0;
  if (node >= NNODE) {
    if (VW==4) { *(uint2*)&hh[ofs] = make_uint2(0,0); *(uint2*)&hl[ofs] = make_uint2(0,0); }
    else       { *(unsigned*)&hh[ofs] = 0; *(unsigned*)&hl[ofs] = 0; }
    return;
  }
  float acc[VW] = {};
  int s = row_ptr[node], e = row_ptr[node+1];
  for (int p=s;p<e;p++) {
    float a = alpha[p];
    float v[VW];
    loadrow<VW>(xw + (size_t)col_src[p]*L + c0, c0, L, v);
    #pragma unroll
    for (int j=0;j<VW;j++) acc[j] = fmaf(a, v[j], acc[j]);
  }
  float t[VW], ss = 0.f;
  #pragma unroll
  for (int j=0;j<VW;j++){ int c = c0+j; t[j] = (c<L) ? acc[j]+bias[c] : 0.f; ss += t[j]*t[j]; }
  #pragma unroll
  for (int o=32;o;o>>=1) ss += __shfl_xor(ss, o);
  float inv = 1.0f / fmaxf(sqrtf(ss), 1e-12f);
  u16 hs[VW], ls[VW];
  #pragma unroll
  for (int j=0;j<VW;j++){
    float o2 = (c0+j < L) ? leaky(t[j]*inv) : 0.f;
    hs[j] = f2bf(o2); ls[j] = f2bf(o2 - bf2f(hs[j]));
  }
  if (VW==4) { *(uint2*)&hh[ofs] = make_uint2(pack2(hs[0],hs[1]),pack2(hs[2],hs[3]));
               *(uint2*)&hl[ofs] = make_uint2(pack2(ls[0],ls[1]),pack2(ls[2],ls[3])); }
  else       { *(unsigned*)&hh[ofs] = pack2(hs[0],hs[1]); *(unsigned*)&hl[ofs] = pack2(ls[0],ls[1]); }
}

// scores: rep holds 3*rep_true -> scale dot by 1/9
__global__ __launch_bounds__(256)
void score_k(const float* __restrict__ rep, const int* __restrict__ un,
             const int* __restrict__ pi, const int* __restrict__ ni, float* __restrict__ out)
{
  int wid = (blockIdx.x*blockDim.x + threadIdx.x) >> 6;
  int lane = threadIdx.x & 63;
  if (wid >= 2048) return;
  int i = wid & 1023;
  int isneg = wid >> 10;
  int u = un[i];
  int it = isneg ? ni[i] : pi[i];
  float p = rep[(size_t)u*64 + lane] * rep[(size_t)it*64 + lane];
  #pragma unroll
  for (int o=32;o;o>>=1) p += __shfl_xor(p, o);
  if (lane==0) out[isneg*1024 + i] = p * (1.0f/9.0f);
}

// ---------------- launch ----------------
static inline size_t align_up(size_t v){ return (v + 255) & ~(size_t)255; }
static inline int cdiv(int a, int b){ return (a + b - 1) / b; }

extern "C" void kernel_launch(void* const* d_in, const int* in_sizes, int n_in,
                              void* d_out, int out_size, void* d_ws, size_t ws_size,
                              hipStream_t stream)
{
  const int E  = in_sizes[31] / 2;   // 250000
  const int E2 = 2*E;

  char* p = (char*)d_ws;
  auto carve = [&](size_t bytes){ char* r = p; p += align_up(bytes); return r; };
  float* x      = (float*)carve((size_t)NNODE*256*4);
  float* xw     = (float*)carve((size_t)NNODE*256*4);
  u16*   xh     = (u16*)carve((size_t)MP_NODE*256*2);
  u16*   xl     = (u16*)carve((size_t)MP_NODE*256*2);
  float* xhat   = (float*)carve((size_t)NNODE*64*4);
  float* rep    = (float*)carve((size_t)NNODE*64*4);
  float* alpha  = (float*)carve((size_t)E2*4);
  int* deg      = (int*)carve((size_t)NNODE*4);
  int* row_ptr  = (int*)carve((size_t)(NNODE+1)*4);
  int* row_fill = (int*)carve((size_t)NNODE*4);
  int* col_src  = (int*)carve((size_t)E2*4);

  const int* ei = (const int*)d_in[31];
  const float* id_emb = (const float*)d_in[30];

  struct Mod { const float *feat,*pref,*mlp_w,*mlp_b,*conv_w,*conv_b,*lin_w,*lin_b,*g_w,*g_b;
               int Fd, L, Kpx, Kpf, NpL; };
  Mod md[3];
  for (int m=0;m<3;m++) {
    int b = m*10;
    md[m].feat   = (const float*)d_in[b+0];
    md[m].pref   = (const float*)d_in[b+1];
    md[m].mlp_w  = (const float*)d_in[b+2];
    md[m].mlp_b  = (const float*)d_in[b+3];
    md[m].conv_w = (const float*)d_in[b+4];
    md[m].conv_b = (const float*)d_in[b+5];
    md[m].lin_w  = (const float*)d_in[b+6];
    md[m].lin_b  = (const float*)d_in[b+7];
    md[m].g_w    = (const float*)d_in[b+8];
    md[m].g_b    = (const float*)d_in[b+9];
  }
  md[0].Fd=2048; md[0].L=256; md[0].Kpx=256; md[0].Kpf=2048; md[0].NpL=256;
  md[1].Fd=128;  md[1].L=128; md[1].Kpx=128; md[1].Kpf=128;  md[1].NpL=128;
  md[2].Fd=100;  md[2].L=100; md[2].Kpx=128; md[2].Kpf=128;  md[2].NpL=128;

  u16 *wmh[3],*wml[3],*wch[3],*wcl[3],*wlh[3],*wll[3],*wgh[3],*wgl[3];
  WPack P;
  int maxTot = 0;
  for (int m=0;m<3;m++) {
    const Mod& M_ = md[m];
    size_t smlp = (size_t)M_.NpL*M_.Kpf*2, sconv = (size_t)M_.NpL*M_.Kpx*2, slin = (size_t)64*M_.Kpx*2;
    wmh[m]=(u16*)carve(smlp); wml[m]=(u16*)carve(smlp);
    wch[m]=(u16*)carve(sconv); wcl[m]=(u16*)carve(sconv);
    wlh[m]=(u16*)carve(slin);  wll[m]=(u16*)carve(slin);
    wgh[m]=(u16*)carve(slin);  wgl[m]=(u16*)carve(slin);
    P.d[m*4+0] = { M_.mlp_w,  wmh[m], wml[m], M_.Fd, M_.L, M_.Kpf, M_.NpL };
    P.d[m*4+1] = { M_.conv_w, wch[m], wcl[m], M_.L,  M_.L, M_.Kpx, M_.NpL };
    P.d[m*4+2] = { M_.lin_w,  wlh[m], wll[m], M_.L,  64,   M_.Kpx, 64 };
    P.d[m*4+3] = { M_.g_w,    wgh[m], wgl[m], M_.L,  64,   M_.Kpx, 64 };
    for (int q=0;q<4;q++){ int t = P.d[m*4+q].Np*P.d[m*4+q].Kp; if (t>maxTot) maxTot=t; }
  }

  hipMemsetAsync(deg, 0, (size_t)NNODE*4, stream);
  hipMemsetAsync(row_fill, 0, (size_t)NNODE*4, stream);
  hipMemsetAsync(rep, 0, (size_t)NNODE*64*4, stream);

  { dim3 g(cdiv(maxTot,256), 12); split_w_k<<<g,256,0,stream>>>(P); }
  {
    int blocks = cdiv(E2, 256);
    count_deg<<<blocks,256,0,stream>>>(ei, deg, E);
    scan_rowptr<<<1,256,0,stream>>>(deg, row_ptr, NNODE);
    fill_csr<<<blocks,256,0,stream>>>(ei, row_ptr, row_fill, col_src, E);
  }

  for (int m=0;m<3;m++) {
    const Mod& M_ = md[m];
    const int L = M_.L;

    // x[0:NUSER) = pref ; x[NUSER:) = tanh(feat @ mlp_w + b)
    hipMemcpyAsync(x, M_.pref, (size_t)NUSER*L*4, hipMemcpyDeviceToDevice, stream);
    if (m == 0)
      wgemm_k<64,256,EPI_TANH,false><<<dim3(1,MP_USER/64),512,0,stream>>>(
          M_.feat, nullptr, nullptr, wmh[m], wml[m], M_.mlp_b, nullptr,
          x + (size_t)NUSER*L, NUSER, L, M_.Fd, M_.Kpf);
    else
      wgemm_k<64,128,EPI_TANH,false><<<dim3(1,MP_USER/64),256,0,stream>>>(
          M_.feat, nullptr, nullptr, wmh[m], wml[m], M_.mlp_b, nullptr,
          x + (size_t)NUSER*L, NUSER, L, M_.Fd, M_.Kpf);

    if (M_.Kpx==256) l2norm_split_k<4><<<MP_NODE/4,256,0,stream>>>(x, xh, xl, L, M_.Kpx);
    else             l2norm_split_k<2><<<MP_NODE/4,256,0,stream>>>(x, xh, xl, L, M_.Kpx);

    // xw = x @ conv_w
    if (m == 0)
      wgemm_k<64,256,EPI_STORE,true><<<dim3(1,MP_NODE/64),512,0,stream>>>(
          nullptr, xh, xl, wch[m], wcl[m], nullptr, nullptr, xw, NNODE, L, L, M_.Kpx);
    else
      wgemm_k<64,128,EPI_STORE,true><<<dim3(1,MP_NODE/64),256,0,stream>>>(
          nullptr, xh, xl, wch[m], wcl[m], nullptr, nullptr, xw, NNODE, L, L, M_.Kpx);

    // xhat = leaky(x @ lin_w + b) + id_emb
    wgemm_k<128,64,EPI_LEAKY_ADD,true><<<dim3(1,MP_NODE/128),256,0,stream>>>(
        nullptr, xh, xl, wlh[m], wll[m], M_.lin_b, id_emb, xhat, NNODE, 64, L, M_.Kpx);

    // fused edge logits + softmax -> alpha
    if (L==256) gat_alpha_k<4><<<NNODE/4,256,0,stream>>>(xw, row_ptr, col_src, deg, alpha, L);
    else        gat_alpha_k<2><<<NNODE/4,256,0,stream>>>(xw, row_ptr, col_src, deg, alpha, L);

    // aggregate -> h (bf16 split into xh/xl)
    if (M_.Kpx==256) aggregate_k<4><<<MP_NODE/4,256,0,stream>>>(xw, alpha, row_ptr, col_src, M_.conv_b, xh, xl, L, M_.Kpx);
    else             aggregate_k<2><<<MP_NODE/4,256,0,stream>>>(xw, alpha, row_ptr, col_src, M_.conv_b, xh, xl, L, M_.Kpx);

    // rep += leaky(h @ g_w + g_b + xhat)
    wgemm_k<128,64,EPI_ACCUM,true><<<dim3(1,MP_NODE/128),256,0,stream>>>(
        nullptr, xh, xl, wgh[m], wgl[m], M_.g_b, xhat, rep, NNODE, 64, L, M_.Kpx);
  }

  score_k<<<cdiv(2048*64,256),256,0,stream>>>(rep, (const int*)d_in[32], (const int*)d_in[33],
                                              (const int*)d_in[34], (float*)d_out);
}

// Round 5
// 1171.241 us; speedup vs baseline: 1.2641x; 1.2641x over previous
//
#include <hip/hip_runtime.h>
#include <math.h>

#define NUSER 20000
#define NITEM 20000
#define NNODE 40000
#define MP_USER 20096   // 314*64
#define MP_NODE 40064   // 626*64 = 313*128

typedef unsigned short u16;
typedef __attribute__((ext_vector_type(8))) short bf16x8;   // 8 bf16 = 4 VGPRs
typedef __attribute__((ext_vector_type(4))) float f32x4;

__device__ __forceinline__ float leaky(float v){ return v > 0.0f ? v : 0.01f*v; }
__device__ __forceinline__ u16 f2bf(float f){
  unsigned u = __float_as_uint(f);
  return (u16)((u + 0x7FFFu + ((u>>16)&1u)) >> 16);   // RNE bf16
}
__device__ __forceinline__ float bf2f(u16 h){ return __uint_as_float(((unsigned)h)<<16); }
__device__ __forceinline__ unsigned pack2(u16 a, u16 b){ return (unsigned)a | ((unsigned)b<<16); }

enum { EPI_STORE=0, EPI_TANH=1, EPI_LEAKY_ADD=2, EPI_ACCUM=3, EPI_NONE=4 };

// ================= MFMA GEMM: C[M,N] = epi(A[M,K] @ W[K,N]) =================
// Wave tile (MI*16)x64 -> MI*4*3 MFMA per 2*(MI+4) frag reads (3:1 at MI=4).
// XOR-swizzled LDS: granule(r,kk) at G = kk*BM + (r ^ (kk<<1)); staging writes and
// frag reads both <=2-way bank aliasing (free, m136). BK=32.
// SPLITK>1: EPI_NONE partials at C + z*MP_USER*N (padded rows, no guards).
template<int WR, int WC, int MI, int EPI, bool ASPLIT, int SPLITK>
__global__ __launch_bounds__(WR*WC*64)
void wgemm_k(const float* __restrict__ A, const u16* __restrict__ Ah, const u16* __restrict__ Al,
             const u16* __restrict__ Bh, const u16* __restrict__ Bl,
             const float* __restrict__ bias, const float* __restrict__ add,
             float* __restrict__ C, int M, int N, int K, int Kp)
{
  constexpr int BM = WR*MI*16, BN = WC*64, T = WR*WC*64, NI = 4;
  __shared__ u16 Ash[4*BM*8], Asl[4*BM*8], Bsh[4*BN*8], Bsl[4*BN*8];
  const int tid = threadIdx.x, lane = tid & 63, wid = tid >> 6;
  const int wrow = wid / WC, wcol = wid % WC;
  const int row0 = blockIdx.y*BM;
  const int fr = lane & 15, kg = lane >> 4;
  const int Kc = Kp / SPLITK;
  const int ks0 = (SPLITK > 1) ? blockIdx.z * Kc : 0;

  f32x4 acc[MI][NI] = {};

  for (int kt = 0; kt < Kc; kt += 32) {
    // ---- stage A ----
    if (ASPLIT) {
      constexpr int AG = BM*4;
      #pragma unroll
      for (int i = 0; i < 2*AG/T; i++) {
        int g = tid + i*T;
        int gi = (g < AG) ? g : g - AG;
        int r = gi >> 2, kk = gi & 3;
        size_t ofs = (size_t)(row0+r)*Kp + ks0 + kt + kk*8;
        int G = (kk*BM + (r ^ (kk<<1)))*8;
        if (g < AG) *(uint4*)&Ash[G] = *(const uint4*)(Ah + ofs);
        else        *(uint4*)&Asl[G] = *(const uint4*)(Al + ofs);
      }
    } else {
      constexpr int AG = BM*4;   // 8-float granules
      #pragma unroll
      for (int i = 0; i < AG/T; i++) {
        int g = tid + i*T;
        int r = g >> 2, kk = g & 3;
        int gr = row0 + r, gk = ks0 + kt + kk*8;
        float fv[8];
        if (gr < M && gk + 8 <= K) {
          *(float4*)&fv[0] = *(const float4*)(A + (size_t)gr*K + gk);
          *(float4*)&fv[4] = *(const float4*)(A + (size_t)gr*K + gk + 4);
        } else {
          #pragma unroll
          for (int j=0;j<8;j++) fv[j] = (gr < M && gk + j < K) ? A[(size_t)gr*K + gk + j] : 0.f;
        }
        u16 hs[8], ls[8];
        #pragma unroll
        for (int j=0;j<8;j++){ u16 h = f2bf(fv[j]); hs[j]=h; ls[j]=f2bf(fv[j]-bf2f(h)); }
        int G = (kk*BM + (r ^ (kk<<1)))*8;
        *(uint4*)&Ash[G] = make_uint4(pack2(hs[0],hs[1]),pack2(hs[2],hs[3]),pack2(hs[4],hs[5]),pack2(hs[6],hs[7]));
        *(uint4*)&Asl[G] = make_uint4(pack2(ls[0],ls[1]),pack2(ls[2],ls[3]),pack2(ls[4],ls[5]),pack2(ls[6],ls[7]));
      }
    }
    // ---- stage B ----
    {
      constexpr int BG = BN*4;
      #pragma unroll
      for (int i = 0; i < 2*BG/T; i++) {
        int g = tid + i*T;
        int gi = (g < BG) ? g : g - BG;
        int r = gi >> 2, kk = gi & 3;
        size_t ofs = (size_t)r*Kp + ks0 + kt + kk*8;
        int G = (kk*BN + (r ^ (kk<<1)))*8;
        if (g < BG) *(uint4*)&Bsh[G] = *(const uint4*)(Bh + ofs);
        else        *(uint4*)&Bsl[G] = *(const uint4*)(Bl + ofs);
      }
    }
    __syncthreads();
    // ---- frags + MFMA ----
    bf16x8 ah_[MI], al_[MI], bh_[NI], bl_[NI];
    #pragma unroll
    for (int mi=0;mi<MI;mi++){
      int rw = wrow*(MI*16) + mi*16 + fr;
      int G = (kg*BM + (rw ^ (kg<<1)))*8;
      ah_[mi] = *(const bf16x8*)&Ash[G];
      al_[mi] = *(const bf16x8*)&Asl[G];
    }
    #pragma unroll
    for (int ni=0;ni<NI;ni++){
      int cw = wcol*64 + ni*16 + fr;
      int G = (kg*BN + (cw ^ (kg<<1)))*8;
      bh_[ni] = *(const bf16x8*)&Bsh[G];
      bl_[ni] = *(const bf16x8*)&Bsl[G];
    }
    #pragma unroll
    for (int mi=0;mi<MI;mi++)
      #pragma unroll
      for (int ni=0;ni<NI;ni++){
        acc[mi][ni] = __builtin_amdgcn_mfma_f32_16x16x32_bf16(ah_[mi], bh_[ni], acc[mi][ni], 0,0,0);
        acc[mi][ni] = __builtin_amdgcn_mfma_f32_16x16x32_bf16(ah_[mi], bl_[ni], acc[mi][ni], 0,0,0);
        acc[mi][ni] = __builtin_amdgcn_mfma_f32_16x16x32_bf16(al_[mi], bh_[ni], acc[mi][ni], 0,0,0);
      }
    __syncthreads();
  }
  // ---- epilogue: D reg r -> row=(lane>>4)*4+r, col=lane&15 (m89-verified) ----
  float* Cb = (EPI==EPI_NONE) ? (C + (size_t)blockIdx.z*MP_USER*N) : C;
  #pragma unroll
  for (int mi=0;mi<MI;mi++){
    #pragma unroll
    for (int ni=0;ni<NI;ni++){
      int col = wcol*64 + ni*16 + fr;
      if (EPI!=EPI_NONE && col >= N) continue;
      #pragma unroll
      for (int r=0;r<4;r++){
        int row = row0 + wrow*(MI*16) + mi*16 + kg*4 + r;
        if (EPI!=EPI_NONE && row >= M) continue;
        size_t idx = (size_t)row*N + col;
        float v = acc[mi][ni][r];
        if (EPI==EPI_NONE)           Cb[idx] = v;
        else if (EPI==EPI_STORE)     Cb[idx] = v;
        else if (EPI==EPI_TANH)      Cb[idx] = tanhf(v + bias[col]);
        else if (EPI==EPI_LEAKY_ADD) Cb[idx] = leaky(v + bias[col]) + add[idx];
        else                         Cb[idx] += leaky(v + bias[col] + add[idx]);
      }
    }
  }
}

// ============ weight pre-split: W[K][N] fp32 -> Wt_hi/Wt_lo[Np][Kp] bf16 ============
struct WDesc { const float* w; u16 *th, *tl; int K, N, Kp, Np; };
struct WPack { WDesc d[12]; };
__global__ void split_w_k(WPack P)
{
  WDesc D = P.d[blockIdx.y];
  int gid = blockIdx.x*256 + threadIdx.x;
  int tot = D.Np * D.Kp;
  if (gid >= tot) return;
  int k = gid / D.Np, n = gid % D.Np;
  float v = (k < D.K && n < D.N) ? D.w[(size_t)k*D.N + n] : 0.f;
  u16 h = f2bf(v);
  D.th[(size_t)n*D.Kp + k] = h;
  D.tl[(size_t)n*D.Kp + k] = f2bf(v - bf2f(h));
}

// ---------------- graph structure ----------------
// doubled edges: src(e)=ei[e]; dst(e)= e<E ? ei[e+E] : ei[e-E]
__global__ void count_deg(const int* __restrict__ ei, int* __restrict__ deg, int E)
{
  int e = blockIdx.x*blockDim.x + threadIdx.x;
  if (e >= 2*E) return;
  int dst = (e < E) ? ei[e+E] : ei[e-E];
  atomicAdd(&deg[dst], 1);
}

// wave-scan version: 1024 elems/iter, 2 barriers/iter (old 256/iter, 16 barriers: ~45us)
__global__ void scan_rowptr(const int* __restrict__ deg, int* __restrict__ row_ptr, int n)
{
  __shared__ int wsum[4];
  __shared__ int carry;
  int tid = threadIdx.x, lane = tid & 63, wid = tid >> 6;
  if (tid==0) carry = 0;
  __syncthreads();
  for (int base=0; base<n; base+=1024) {
    int i0 = base + tid*4;
    int d[4];
    #pragma unroll
    for (int k=0;k<4;k++) d[k] = (i0+k < n) ? deg[i0+k] : 0;
    int t = d[0]+d[1]+d[2]+d[3];
    int incl = t;
    #pragma unroll
    for (int o=1;o<64;o<<=1){ int v = __shfl_up(incl, o); if (lane >= o) incl += v; }
    if (lane==63) wsum[wid] = incl;
    __syncthreads();
    int pre = carry;
    for (int w=0; w<wid; w++) pre += wsum[w];
    int run = pre + incl - t;
    #pragma unroll
    for (int k=0;k<4;k++){ run += d[k]; if (i0+k < n) row_ptr[i0+k+1] = run; }
    __syncthreads();
    if (tid==0) carry += wsum[0]+wsum[1]+wsum[2]+wsum[3];
  }
  if (tid==0) row_ptr[0] = 0;
}

__global__ void fill_csr(const int* __restrict__ ei, const int* __restrict__ row_ptr,
                         int* __restrict__ row_fill, int* __restrict__ col_src,
                         int* __restrict__ col_dst, int E)
{
  int e = blockIdx.x*blockDim.x + threadIdx.x;
  if (e >= 2*E) return;
  int src = ei[e];
  int dst = (e < E) ? ei[e+E] : ei[e-E];
  int pos = row_ptr[dst] + atomicAdd(&row_fill[dst], 1);
  col_src[pos] = src;
  col_dst[pos] = dst;
}

// guarded vector row load
template<int VW>
__device__ __forceinline__ void loadrow(const float* __restrict__ r, int c0, int L, float* v){
  if (c0 + VW <= L) {
    if (VW==4) *(float4*)v = *(const float4*)r;
    else       *(float2*)v = *(const float2*)r;
  } else {
    #pragma unroll
    for (int j=0;j<VW;j++) v[j] = (c0+j < L) ? r[j] : 0.f;
  }
}

// ---------------- l2norm + bf16 split; folds mlp partial-sum reduce + bias + tanh ----------------
// rows < NUSER: from pref; rows [NUSER,NNODE): tanh(xp0(+xp1)+bias); pad rows: zero
template<int VW>
__global__ __launch_bounds__(256)
void l2norm_split_k(const float* __restrict__ pref, const float* __restrict__ xp0,
                    const float* __restrict__ xp1, const float* __restrict__ bias,
                    u16* __restrict__ xh, u16* __restrict__ xl, int L, int Kp)
{
  int row = (blockIdx.x*blockDim.x + threadIdx.x) >> 6;
  int lane = threadIdx.x & 63;
  if (row >= MP_NODE) return;
  int c0 = lane*VW;
  size_t ofs = (size_t)row*Kp + c0;
  if (row >= NNODE) {
    if (VW==4) { *(uint2*)&xh[ofs] = make_uint2(0,0); *(uint2*)&xl[ofs] = make_uint2(0,0); }
    else       { *(unsigned*)&xh[ofs] = 0; *(unsigned*)&xl[ofs] = 0; }
    return;
  }
  float v[VW];
  if (row < NUSER) {
    loadrow<VW>(pref + (size_t)row*L + c0, c0, L, v);
  } else {
    int i = row - NUSER;
    float a[VW], b[VW];
    size_t po = (size_t)i*Kp + c0;   // xp padded to Kp cols, MP_USER rows
    if (VW==4) *(float4*)a = *(const float4*)(xp0 + po);
    else       *(float2*)a = *(const float2*)(xp0 + po);
    if (xp1) { if (VW==4) *(float4*)b = *(const float4*)(xp1 + po);
               else       *(float2*)b = *(const float2*)(xp1 + po); }
    #pragma unroll
    for (int j=0;j<VW;j++){
      int c = c0+j;
      float s = a[j] + (xp1 ? b[j] : 0.f) + ((c<L) ? bias[c] : 0.f);
      v[j] = (c<L) ? tanhf(s) : 0.f;
    }
  }
  float ss = 0.f;
  #pragma unroll
  for (int j=0;j<VW;j++) ss += v[j]*v[j];
  #pragma unroll
  for (int o=32;o;o>>=1) ss += __shfl_xor(ss, o);
  float inv = 1.0f / fmaxf(sqrtf(ss), 1e-12f);
  u16 hs[VW], ls[VW];
  #pragma unroll
  for (int j=0;j<VW;j++){
    float val = (c0+j < L) ? v[j]*inv : 0.f;
    hs[j] = f2bf(val); ls[j] = f2bf(val - bf2f(hs[j]));
  }
  if (VW==4) { *(uint2*)&xh[ofs] = make_uint2(pack2(hs[0],hs[1]),pack2(hs[2],hs[3]));
               *(uint2*)&xl[ofs] = make_uint2(pack2(ls[0],ls[1]),pack2(ls[2],ls[3])); }
  else       { *(unsigned*)&xh[ofs] = pack2(hs[0],hs[1]); *(unsigned*)&xl[ofs] = pack2(ls[0],ls[1]); }
}

// ---------------- edge-parallel logits over CSR slots: 16 lanes per edge ----------------
__global__ __launch_bounds__(256)
void edge_logits_k(const float* __restrict__ xw, const int* __restrict__ col_src,
                   const int* __restrict__ col_dst, const int* __restrict__ deg,
                   float* __restrict__ logits, int L, int E2)
{
  int p = (blockIdx.x*blockDim.x + threadIdx.x) >> 4;
  int j = threadIdx.x & 15;
  if (p >= E2) return;
  int src = col_src[p], dst = col_dst[p];
  const float* ps = xw + (size_t)src*L;
  const float* pd = xw + (size_t)dst*L;
  float dot = 0.f;
  for (int c = j*4; c < L; c += 64) {
    float4 a = *(const float4*)(ps + c);
    float4 b = *(const float4*)(pd + c);
    dot += a.x*b.x + a.y*b.y + a.z*b.z + a.w*b.w;
  }
  #pragma unroll
  for (int o=8;o;o>>=1) dot += __shfl_xor(dot, o, 16);
  if (j==0) {
    float t = dot / sqrtf((float)deg[src]);
    float gate = 1.0f/(1.0f + expf(-t));
    logits[p] = dot * gate;
  }
}

// ---------------- per-dst softmax over contiguous CSR range ----------------
__global__ __launch_bounds__(256)
void node_softmax(const float* __restrict__ logits, const int* __restrict__ row_ptr,
                  float* __restrict__ alpha, int n)
{
  int node = (blockIdx.x*blockDim.x + threadIdx.x) >> 6;
  int lane = threadIdx.x & 63;
  if (node >= n) return;
  int s = row_ptr[node], e = row_ptr[node+1];
  int cnt = e - s;
  if (cnt == 0) return;
  if (cnt <= 64) {
    float lv = (lane < cnt) ? logits[s+lane] : -INFINITY;
    float m = lv;
    #pragma unroll
    for (int o=32;o;o>>=1) m = fmaxf(m, __shfl_xor(m, o));
    float el = (lane < cnt) ? expf(lv - m) : 0.f;
    float d = el;
    #pragma unroll
    for (int o=32;o;o>>=1) d += __shfl_xor(d, o);
    if (lane < cnt) alpha[s+lane] = el / fmaxf(d, 1e-16f);
  } else {
    float m = -INFINITY;
    for (int q=s+lane;q<e;q+=64) m = fmaxf(m, logits[q]);
    #pragma unroll
    for (int o=32;o;o>>=1) m = fmaxf(m, __shfl_xor(m, o));
    float d = 0.f;
    for (int q=s+lane;q<e;q+=64) d += expf(logits[q]-m);
    #pragma unroll
    for (int o=32;o;o>>=1) d += __shfl_xor(d, o);
    float inv = 1.0f / fmaxf(d, 1e-16f);
    for (int q=s+lane;q<e;q+=64) alpha[q] = expf(logits[q]-m)*inv;
  }
}

// ---------------- aggregate -> h (bf16 split), one wave per node ----------------
template<int VW>
__global__ __launch_bounds__(256)
void aggregate_k(const float* __restrict__ xw, const float* __restrict__ alpha,
                 const int* __restrict__ row_ptr, const int* __restrict__ col_src,
                 const float* __restrict__ bias, u16* __restrict__ hh, u16* __restrict__ hl,
                 int L, int Kp)
{
  int node = (blockIdx.x*blockDim.x + threadIdx.x) >> 6;
  int lane = threadIdx.x & 63;
  if (node >= MP_NODE) return;
  int c0 = lane*VW;
  size_t ofs = (size_t)node*Kp + c0;
  if (node >= NNODE) {
    if (VW==4) { *(uint2*)&hh[ofs] = make_uint2(0,0); *(uint2*)&hl[ofs] = make_uint2(0,0); }
    else       { *(unsigned*)&hh[ofs] = 0; *(unsigned*)&hl[ofs] = 0; }
    return;
  }
  float acc[VW] = {};
  int s = row_ptr[node], e = row_ptr[node+1];
  for (int p=s;p<e;p++) {
    float a = alpha[p];
    float v[VW];
    loadrow<VW>(xw + (size_t)col_src[p]*L + c0, c0, L, v);
    #pragma unroll
    for (int j=0;j<VW;j++) acc[j] = fmaf(a, v[j], acc[j]);
  }
  float t[VW], ss = 0.f;
  #pragma unroll
  for (int j=0;j<VW;j++){ int c = c0+j; t[j] = (c<L) ? acc[j]+bias[c] : 0.f; ss += t[j]*t[j]; }
  #pragma unroll
  for (int o=32;o;o>>=1) ss += __shfl_xor(ss, o);
  float inv = 1.0f / fmaxf(sqrtf(ss), 1e-12f);
  u16 hs[VW], ls[VW];
  #pragma unroll
  for (int j=0;j<VW;j++){
    float o2 = (c0+j < L) ? leaky(t[j]*inv) : 0.f;
    hs[j] = f2bf(o2); ls[j] = f2bf(o2 - bf2f(hs[j]));
  }
  if (VW==4) { *(uint2*)&hh[ofs] = make_uint2(pack2(hs[0],hs[1]),pack2(hs[2],hs[3]));
               *(uint2*)&hl[ofs] = make_uint2(pack2(ls[0],ls[1]),pack2(ls[2],ls[3])); }
  else       { *(unsigned*)&hh[ofs] = pack2(hs[0],hs[1]); *(unsigned*)&hl[ofs] = pack2(ls[0],ls[1]); }
}

// scores: rep holds 3*rep_true -> scale dot by 1/9
__global__ __launch_bounds__(256)
void score_k(const float* __restrict__ rep, const int* __restrict__ un,
             const int* __restrict__ pi, const int* __restrict__ ni, float* __restrict__ out)
{
  int wid = (blockIdx.x*blockDim.x + threadIdx.x) >> 6;
  int lane = threadIdx.x & 63;
  if (wid >= 2048) return;
  int i = wid & 1023;
  int isneg = wid >> 10;
  int u = un[i];
  int it = isneg ? ni[i] : pi[i];
  float p = rep[(size_t)u*64 + lane] * rep[(size_t)it*64 + lane];
  #pragma unroll
  for (int o=32;o;o>>=1) p += __shfl_xor(p, o);
  if (lane==0) out[isneg*1024 + i] = p * (1.0f/9.0f);
}

// ---------------- launch ----------------
static inline size_t align_up(size_t v){ return (v + 255) & ~(size_t)255; }
static inline int cdiv(int a, int b){ return (a + b - 1) / b; }

extern "C" void kernel_launch(void* const* d_in, const int* in_sizes, int n_in,
                              void* d_out, int out_size, void* d_ws, size_t ws_size,
                              hipStream_t stream)
{
  const int E  = in_sizes[31] / 2;   // 250000
  const int E2 = 2*E;

  char* p = (char*)d_ws;
  auto carve = [&](size_t bytes){ char* r = p; p += align_up(bytes); return r; };
  float* xw     = (float*)carve((size_t)NNODE*256*4);
  float* xp     = (float*)carve((size_t)2*MP_USER*256*4);  // split-K partials (chunk stride MP_USER*N)
  u16*   xh     = (u16*)carve((size_t)MP_NODE*256*2);
  u16*   xl     = (u16*)carve((size_t)MP_NODE*256*2);
  float* xhat   = (float*)carve((size_t)NNODE*64*4);
  float* rep    = (float*)carve((size_t)NNODE*64*4);
  float* logits = (float*)carve((size_t)E2*4);
  float* alpha  = (float*)carve((size_t)E2*4);
  int* deg      = (int*)carve((size_t)NNODE*4);
  int* row_ptr  = (int*)carve((size_t)(NNODE+1)*4);
  int* row_fill = (int*)carve((size_t)NNODE*4);
  int* col_src  = (int*)carve((size_t)E2*4);
  int* col_dst  = (int*)carve((size_t)E2*4);

  const int* ei = (const int*)d_in[31];
  const float* id_emb = (const float*)d_in[30];

  struct Mod { const float *feat,*pref,*mlp_w,*mlp_b,*conv_w,*conv_b,*lin_w,*lin_b,*g_w,*g_b;
               int Fd, L, Kpx, Kpf, NpL; };
  Mod md[3];
  for (int m=0;m<3;m++) {
    int b = m*10;
    md[m].feat   = (const float*)d_in[b+0];
    md[m].pref   = (const float*)d_in[b+1];
    md[m].mlp_w  = (const float*)d_in[b+2];
    md[m].mlp_b  = (const float*)d_in[b+3];
    md[m].conv_w = (const float*)d_in[b+4];
    md[m].conv_b = (const float*)d_in[b+5];
    md[m].lin_w  = (const float*)d_in[b+6];
    md[m].lin_b  = (const float*)d_in[b+7];
    md[m].g_w    = (const float*)d_in[b+8];
    md[m].g_b    = (const float*)d_in[b+9];
  }
  md[0].Fd=2048; md[0].L=256; md[0].Kpx=256; md[0].Kpf=2048; md[0].NpL=256;
  md[1].Fd=128;  md[1].L=128; md[1].Kpx=128; md[1].Kpf=128;  md[1].NpL=128;
  md[2].Fd=100;  md[2].L=100; md[2].Kpx=128; md[2].Kpf=128;  md[2].NpL=128;

  u16 *wmh[3],*wml[3],*wch[3],*wcl[3],*wlh[3],*wll[3],*wgh[3],*wgl[3];
  WPack P;
  int maxTot = 0;
  for (int m=0;m<3;m++) {
    const Mod& M_ = md[m];
    size_t smlp = (size_t)M_.NpL*M_.Kpf*2, sconv = (size_t)M_.NpL*M_.Kpx*2, slin = (size_t)64*M_.Kpx*2;
    wmh[m]=(u16*)carve(smlp); wml[m]=(u16*)carve(smlp);
    wch[m]=(u16*)carve(sconv); wcl[m]=(u16*)carve(sconv);
    wlh[m]=(u16*)carve(slin);  wll[m]=(u16*)carve(slin);
    wgh[m]=(u16*)carve(slin);  wgl[m]=(u16*)carve(slin);
    P.d[m*4+0] = { M_.mlp_w,  wmh[m], wml[m], M_.Fd, M_.L, M_.Kpf, M_.NpL };
    P.d[m*4+1] = { M_.conv_w, wch[m], wcl[m], M_.L,  M_.L, M_.Kpx, M_.NpL };
    P.d[m*4+2] = { M_.lin_w,  wlh[m], wll[m], M_.L,  64,   M_.Kpx, 64 };
    P.d[m*4+3] = { M_.g_w,    wgh[m], wgl[m], M_.L,  64,   M_.Kpx, 64 };
    for (int q=0;q<4;q++){ int t = P.d[m*4+q].Np*P.d[m*4+q].Kp; if (t>maxTot) maxTot=t; }
  }

  hipMemsetAsync(deg, 0, (size_t)NNODE*4, stream);
  hipMemsetAsync(row_fill, 0, (size_t)NNODE*4, stream);
  hipMemsetAsync(rep, 0, (size_t)NNODE*64*4, stream);

  { dim3 g(cdiv(maxTot,256), 12); split_w_k<<<g,256,0,stream>>>(P); }
  {
    int blocks = cdiv(E2, 256);
    count_deg<<<blocks,256,0,stream>>>(ei, deg, E);
    scan_rowptr<<<1,256,0,stream>>>(deg, row_ptr, NNODE);
    fill_csr<<<blocks,256,0,stream>>>(ei, row_ptr, row_fill, col_src, col_dst, E);
  }

  for (int m=0;m<3;m++) {
    const Mod& M_ = md[m];
    const int L = M_.L;

    // mlp partials: xp[chunk] = feat @ mlp_w (chunk of K)
    if (m == 0)
      wgemm_k<1,4,4,EPI_NONE,false,2><<<dim3(1,MP_USER/64,2),256,0,stream>>>(
          M_.feat, nullptr, nullptr, wmh[m], wml[m], nullptr, nullptr,
          xp, NUSER, 256, M_.Fd, M_.Kpf);
    else
      wgemm_k<1,2,4,EPI_NONE,false,1><<<dim3(1,MP_USER/64,1),128,0,stream>>>(
          M_.feat, nullptr, nullptr, wmh[m], wml[m], nullptr, nullptr,
          xp, NUSER, 128, M_.Fd, M_.Kpf);

    // l2norm + reduce partials + bias + tanh -> xh/xl
    {
      const float* xp1 = (m==0) ? (xp + (size_t)MP_USER*256) : nullptr;
      if (M_.Kpx==256) l2norm_split_k<4><<<MP_NODE/4,256,0,stream>>>(M_.pref, xp, xp1, M_.mlp_b, xh, xl, L, M_.Kpx);
      else             l2norm_split_k<2><<<MP_NODE/4,256,0,stream>>>(M_.pref, xp, xp1, M_.mlp_b, xh, xl, L, M_.Kpx);
    }

    // xw = x @ conv_w
    if (m == 0)
      wgemm_k<1,4,4,EPI_STORE,true,1><<<dim3(1,MP_NODE/64,1),256,0,stream>>>(
          nullptr, xh, xl, wch[m], wcl[m], nullptr, nullptr, xw, NNODE, L, L, M_.Kpx);
    else
      wgemm_k<1,2,4,EPI_STORE,true,1><<<dim3(1,MP_NODE/64,1),128,0,stream>>>(
          nullptr, xh, xl, wch[m], wcl[m], nullptr, nullptr, xw, NNODE, L, L, M_.Kpx);

    // xhat = leaky(x @ lin_w + b) + id_emb
    wgemm_k<4,1,2,EPI_LEAKY_ADD,true,1><<<dim3(1,MP_NODE/128,1),256,0,stream>>>(
        nullptr, xh, xl, wlh[m], wll[m], M_.lin_b, id_emb, xhat, NNODE, 64, L, M_.Kpx);

    // edge phase: edge-parallel logits -> node softmax -> aggregate
    edge_logits_k<<<cdiv(E2*16,256),256,0,stream>>>(xw, col_src, col_dst, deg, logits, L, E2);
    node_softmax<<<cdiv(NNODE*64,256),256,0,stream>>>(logits, row_ptr, alpha, NNODE);
    if (M_.Kpx==256) aggregate_k<4><<<MP_NODE/4,256,0,stream>>>(xw, alpha, row_ptr, col_src, M_.conv_b, xh, xl, L, M_.Kpx);
    else             aggregate_k<2><<<MP_NODE/4,256,0,stream>>>(xw, alpha, row_ptr, col_src, M_.conv_b, xh, xl, L, M_.Kpx);

    // rep += leaky(h @ g_w + g_b + xhat)
    wgemm_k<4,1,2,EPI_ACCUM,true,1><<<dim3(1,MP_NODE/128,1),256,0,stream>>>(
        nullptr, xh, xl, wgh[m], wgl[m], M_.g_b, xhat, rep, NNODE, 64, L, M_.Kpx);
  }

  score_k<<<cdiv(2048*64,256),256,0,stream>>>(rep, (const int*)d_in[32], (const int*)d_in[33],
                                              (const int*)d_in[34], (float*)d_out);
}